// Round 5
// baseline (15293.106 us; speedup 1.0000x reference)
//
#include <hip/hip_runtime.h>
#include <cfloat>

// Problem dims (fixed): z_e [32,64,64,64] NCHW fp32, embedding [1024,64] fp32
// Flat rows n = b*4096 + h*64 + w  (N = 131072, D = 64, K = 1024)
// Out layout (concat, fp32): [0]=vq_loss, [1..8388608]=z_q NCHW,
//                            [8388609]=perplexity, [8388610..]=encodings [N,1024]
// ws layout: ws[0]=loss accum (float), ws[1..1024]=counts (int), ws[1025..2048]=e2 (float)

__global__ __launch_bounds__(256) void vq_prep(const float* __restrict__ emb,
                                               float* __restrict__ ws) {
  #pragma clang fp contract(off)
  int gid = blockIdx.x * 256 + threadIdx.x;   // 0..1023
  if (gid == 0) ws[0] = 0.0f;
  ((int*)ws)[1 + gid] = 0;
  // e2[k] = numpy-pairwise sum of squares over 64 elems
  const float* e = emb + (gid << 6);
  float r[8];
  #pragma unroll
  for (int j = 0; j < 8; ++j) r[j] = e[j] * e[j];
  #pragma unroll
  for (int i = 8; i < 64; i += 8) {
    #pragma unroll
    for (int j = 0; j < 8; ++j) { float s = e[i + j] * e[i + j]; r[j] = r[j] + s; }
  }
  ws[1025 + gid] = ((r[0] + r[1]) + (r[2] + r[3])) + ((r[4] + r[5]) + (r[6] + r[7]));
}

// Block = 4 waves = one 64-row group (b,h). Wave w scans k-slice [256w, 256w+256).
// R5: embedding streamed through wave-private double-buffered LDS tiles
// (16 codes = 4KB each) instead of s_load — the 64-SGPR-per-code row made SMEM
// chunk-latency the critical path (R4 est ~350us vs 123us VALU floor).
// Wave-private LDS -> no barriers in the K-loop; DS ops are in-order per wave.
__global__ __launch_bounds__(256, 4) void vq_main(const float* __restrict__ ze,
                                                  const float* __restrict__ emb,
                                                  float* __restrict__ ws,
                                                  float* __restrict__ out) {
  __shared__ float etile[4][2048];   // per-wave dbuf: 2 x 16 codes x 64 f = 32 KB
  __shared__ float sdist[4][64];
  __shared__ int   sidx[4][64];

  int w    = __builtin_amdgcn_readfirstlane(threadIdx.x >> 6);  // uniform slice id
  int lane = threadIdx.x & 63;   // row within group (= spatial w coord)
  int g    = blockIdx.x;         // row group 0..2047
  int b = g >> 6, h = g & 63;
  int n0 = g << 6;               // first flat row of this group

  // ---- load x[64]: z_e[b, d, h, w], coalesced along w per d ----
  const float* xin = ze + (b << 18) + (h << 6) + lane;
  float x[64];
  #pragma unroll
  for (int d = 0; d < 64; ++d) x[d] = xin[d << 12];
  // Pin: asm-defined values can't be rematerialized -> x stays in 64 VGPRs.
  #pragma unroll
  for (int d = 0; d < 64; ++d) asm("" : "+v"(x[d]));

  // ---- x2: replicate numpy pairwise-sum order exactly ----
  float x2;
  {
    #pragma clang fp contract(off)
    float r[8];
    #pragma unroll
    for (int j = 0; j < 8; ++j) r[j] = x[j] * x[j];
    #pragma unroll
    for (int i = 8; i < 64; i += 8) {
      #pragma unroll
      for (int j = 0; j < 8; ++j) { float s = x[i + j] * x[i + j]; r[j] = r[j] + s; }
    }
    x2 = ((r[0] + r[1]) + (r[2] + r[3])) + ((r[4] + r[5]) + (r[6] + r[7]));
  }

  const float* e2w = ws + 1025;
  float* zq  = out + 1;
  float* enc = out + 8388610;

  int k0 = w << 8;               // uniform slice base
  // staging source: slice base in float4 units = k0*64/4 = k0*16
  const float4* Esrc = (const float4*)emb + (k0 << 4);
  float* mytile = &etile[w][0];  // wave-private; buffers at +0 / +1024 floats
  float4* ldsv = (float4*)mytile;

  // zero-stream: wave w zeroes enc[n0+r][k0 .. k0+256), 128 float2 stores/lane,
  // one 512B-contiguous wave-store per 2 codes. enc offset even -> 8B aligned.
  float2* encz = (float2*)enc + ((size_t)n0 << 9) + (w << 7) + lane;
  const float2 z2 = make_float2(0.0f, 0.0f);

  // ---- prologue: stage tile 0 (16 codes = 256 float4, 4 per lane) ----
  float4 pf[4];
  #pragma unroll
  for (int j = 0; j < 4; ++j) pf[j] = Esrc[(j << 6) + lane];
  #pragma unroll
  for (int j = 0; j < 4; ++j) ldsv[(j << 6) + lane] = pf[j];

  float best = FLT_MAX;
  int bidx = k0;

  for (int t = 0; t < 16; ++t) {
    // prefetch tile t+1 into VGPRs (overlaps ~2200cy of compute below)
    if (t < 15) {
      #pragma unroll
      for (int j = 0; j < 4; ++j) pf[j] = Esrc[((t + 1) << 8) + (j << 6) + lane];
    }
    const float4* cur = (const float4*)(mytile + ((t & 1) << 10));
    #pragma unroll
    for (int c = 0; c < 16; ++c) {
      int k = k0 + (t << 4) + c;
      const float4* ck = cur + (c << 4);   // uniform addr -> broadcast ds_read_b128
      float a0 = 0.0f, a1 = 0.0f, a2 = 0.0f, a3 = 0.0f;
      #pragma unroll
      for (int j = 0; j < 16; ++j) {
        float4 ev = ck[j];
        a0 = fmaf(x[(j << 2) + 0], ev.x, a0);
        a1 = fmaf(x[(j << 2) + 1], ev.y, a1);
        a2 = fmaf(x[(j << 2) + 2], ev.z, a2);
        a3 = fmaf(x[(j << 2) + 3], ev.w, a3);
      }
      float acc  = (a0 + a1) + (a2 + a3);
      float t2   = x2 + e2w[k];          // fl(x2 + e2) like numpy broadcast
      float dist = fmaf(-2.0f, acc, t2); // == fl(t2 - fl(2*acc)); 2*acc exact
      if (dist < best) { best = dist; bidx = k; }  // strict < = first-index
      if (c & 1) {  // zero-stream cadence: 1 store per 2 codes
        int k2 = ((t << 4) + c) >> 1;
        encz[((size_t)(k2 >> 1) << 9) + ((k2 & 1) << 6)] = z2;
      }
    }
    // write prefetched tile into the other buffer (DS in-order per wave ->
    // next iteration's ds_reads of this buffer need no barrier)
    if (t < 15) {
      float4* nb = (float4*)(mytile + (((t + 1) & 1) << 10));
      #pragma unroll
      for (int j = 0; j < 4; ++j) nb[(j << 6) + lane] = pf[j];
    }
  }

  // ---- cross-wave argmin combine (slices k-ordered; strict < keeps the
  //      lowest-k winner on ties = numpy first-index argmin) ----
  sdist[w][lane] = best;
  sidx[w][lane]  = bidx;
  __syncthreads();   // also drains all zero-stream stores before 1.0 writes

  float gb = sdist[0][lane];
  int   gi = sidx[0][lane];
  #pragma unroll
  for (int j = 1; j < 4; ++j) {
    float dj = sdist[j][lane];
    int   ij = sidx[j][lane];
    if (dj < gb) { gb = dj; gi = ij; }
  }

  // ---- epilogue: wave 0 only; all x indices compile-time ----
  if (w == 0) {
    const float* esel = emb + (gi << 6);
    float* zqp = zq + (b << 18) + (h << 6) + lane;
    float lsum = 0.0f;
    #pragma unroll
    for (int d = 0; d < 64; ++d) {
      float v = esel[d];           // per-lane gather (256KB table, L2-resident)
      float df = v - x[d];
      lsum = fmaf(df, df, lsum);
      zqp[d << 12] = v;            // coalesced along w
    }
    #pragma unroll
    for (int off = 32; off > 0; off >>= 1) lsum += __shfl_down(lsum, off, 64);
    if (lane == 0) atomicAdd(ws, lsum);
    atomicAdd(&((int*)ws)[1 + gi], 1);
  }

  // one-hot 1.0: written by the slice-owning wave; its zero store to the same
  // address drained at the barrier above.
  if ((gi >> 8) == w) {
    enc[((size_t)(n0 + lane) << 10) + gi] = 1.0f;
  }
}

__global__ __launch_bounds__(1024) void vq_fin(const float* __restrict__ ws,
                                               float* __restrict__ out) {
  __shared__ float sm[16];
  int t = threadIdx.x;  // 0..1023 = k
  const int* counts = (const int*)ws + 1;
  float c = (float)counts[t];
  float p = c * (1.0f / 131072.0f);
  float s = p * logf(p + 1e-10f);
  #pragma unroll
  for (int off = 32; off > 0; off >>= 1) s += __shfl_down(s, off, 64);
  if ((t & 63) == 0) sm[t >> 6] = s;
  __syncthreads();
  if (t == 0) {
    float v = 0.0f;
    #pragma unroll
    for (int i = 0; i < 16; ++i) v += sm[i];
    out[8388609] = expf(-v);               // perplexity
    float m = ws[0] / 8388608.0f;          // mean (z_q - z)^2
    out[0] = 0.25f * m + m;                // commitment + e2z
  }
}

extern "C" void kernel_launch(void* const* d_in, const int* in_sizes, int n_in,
                              void* d_out, int out_size, void* d_ws, size_t ws_size,
                              hipStream_t stream) {
  const float* ze  = (const float*)d_in[0];
  const float* emb = (const float*)d_in[1];
  float* out = (float*)d_out;
  float* ws  = (float*)d_ws;   // needs 2049 * 4B ≈ 8.2 KB
  vq_prep<<<4, 256, 0, stream>>>(emb, ws);
  vq_main<<<2048, 256, 0, stream>>>(ze, emb, ws, out);
  vq_fin<<<1, 1024, 0, stream>>>(ws, out);
}

// Round 6
// 972.742 us; speedup vs baseline: 15.7217x; 15.7217x over previous
//
#include <hip/hip_runtime.h>
#include <cfloat>

// Problem dims (fixed): z_e [32,64,64,64] NCHW fp32, embedding [1024,64] fp32
// Flat rows n = b*4096 + h*64 + w  (N = 131072, D = 64, K = 1024)
// Out layout (concat, fp32): [0]=vq_loss, [1..8388608]=z_q NCHW,
//                            [8388609]=perplexity, [8388610..]=encodings [N,1024]
// ws layout: ws[0]=loss accum (float), ws[1..1024]=counts (int), ws[1025..2048]=e2 (float)

__global__ __launch_bounds__(256) void vq_prep(const float* __restrict__ emb,
                                               float* __restrict__ ws) {
  #pragma clang fp contract(off)
  int gid = blockIdx.x * 256 + threadIdx.x;   // 0..1023
  if (gid == 0) ws[0] = 0.0f;
  ((int*)ws)[1 + gid] = 0;
  // e2[k] = numpy-pairwise sum of squares over 64 elems
  const float* e = emb + (gid << 6);
  float r[8];
  #pragma unroll
  for (int j = 0; j < 8; ++j) r[j] = e[j] * e[j];
  #pragma unroll
  for (int i = 8; i < 64; i += 8) {
    #pragma unroll
    for (int j = 0; j < 8; ++j) { float s = e[i + j] * e[i + j]; r[j] = r[j] + s; }
  }
  ws[1025 + gid] = ((r[0] + r[1]) + (r[2] + r[3])) + ((r[4] + r[5]) + (r[6] + r[7]));
}

// Block = 4 waves = one 64-row group (b,h). Wave w scans k-slice [256w, 256w+256).
// e-stream via s_load (SGPRs, zero VGPR cost). SMEM returns out-of-order ->
// lgkmcnt(0) drain per code -> latency-bound; throughput scales with resident
// waves (R3: 2w/SIMD=705us, R4: 4w/SIMD=372us). R6: __launch_bounds__(256,6)
// -> VGPR cap 85 -> 6 waves/SIMD. K-loop live set ~74 VGPRs (64 pinned x +
// ~10 temps) fits. Spill canary: VGPR_Count=64 + WRITE_SIZE >> 600MB.
__global__ __launch_bounds__(256, 6) void vq_main(const float* __restrict__ ze,
                                                  const float* __restrict__ emb,
                                                  float* __restrict__ ws,
                                                  float* __restrict__ out) {
  __shared__ float sdist[4][64];
  __shared__ int   sidx[4][64];

  int w    = __builtin_amdgcn_readfirstlane(threadIdx.x >> 6);  // uniform slice id
  int lane = threadIdx.x & 63;   // row within group (= spatial w coord)
  int g    = blockIdx.x;         // row group 0..2047
  int b = g >> 6, h = g & 63;
  int n0 = g << 6;               // first flat row of this group

  // ---- load x[64]: z_e[b, d, h, w], coalesced along w per d ----
  const float* xin = ze + (b << 18) + (h << 6) + lane;
  float x[64];
  #pragma unroll
  for (int d = 0; d < 64; ++d) x[d] = xin[d << 12];
  // Pin: asm-defined values can't be rematerialized -> x stays in 64 VGPRs.
  #pragma unroll
  for (int d = 0; d < 64; ++d) asm("" : "+v"(x[d]));

  // ---- x2: replicate numpy pairwise-sum order exactly ----
  float x2;
  {
    #pragma clang fp contract(off)
    float r[8];
    #pragma unroll
    for (int j = 0; j < 8; ++j) r[j] = x[j] * x[j];
    #pragma unroll
    for (int i = 8; i < 64; i += 8) {
      #pragma unroll
      for (int j = 0; j < 8; ++j) { float s = x[i + j] * x[i + j]; r[j] = r[j] + s; }
    }
    x2 = ((r[0] + r[1]) + (r[2] + r[3])) + ((r[4] + r[5]) + (r[6] + r[7]));
  }

  const float* e2w = ws + 1025;
  float* zq  = out + 1;
  float* enc = out + 8388610;

  int k0 = w << 8;               // uniform slice base
  const float4* E4 = (const float4*)emb;

  // zero-stream: wave w zeroes enc[n0+r][k0 .. k0+256) for r=0..63.
  // 128 float2 stores/lane, one 512B-contiguous store per k2 pair.
  float2* encz = (float2*)enc + ((size_t)n0 << 9) + (w << 7) + lane;
  const float2 z2 = make_float2(0.0f, 0.0f);

  float best = FLT_MAX;
  int bidx = k0;

  for (int k2 = 0; k2 < 128; ++k2) {
    #pragma unroll
    for (int u = 0; u < 2; ++u) {
      int k = k0 + (k2 << 1) + u;
      const float4* ek = E4 + (k << 4);  // uniform -> s_load (SGPRs)
      float a0 = 0.0f, a1 = 0.0f, a2 = 0.0f, a3 = 0.0f;
      #pragma unroll
      for (int j = 0; j < 16; ++j) {
        float4 ev = ek[j];
        a0 = fmaf(x[(j << 2) + 0], ev.x, a0);
        a1 = fmaf(x[(j << 2) + 1], ev.y, a1);
        a2 = fmaf(x[(j << 2) + 2], ev.z, a2);
        a3 = fmaf(x[(j << 2) + 3], ev.w, a3);
      }
      float acc  = (a0 + a1) + (a2 + a3);
      float t    = x2 + e2w[k];          // fl(x2 + e2) like numpy broadcast
      float dist = fmaf(-2.0f, acc, t);  // == fl(t - fl(2*acc)); 2*acc exact
      if (dist < best) { best = dist; bidx = k; }  // strict < = first-index
    }
    encz[((size_t)(k2 >> 1) << 9) + ((k2 & 1) << 6)] = z2;
  }

  // ---- cross-wave argmin combine (slices k-ordered; strict < keeps the
  //      lowest-k winner on ties = numpy first-index argmin) ----
  sdist[w][lane] = best;
  sidx[w][lane]  = bidx;
  __syncthreads();   // also drains all zero-stream stores before 1.0 writes

  float gb = sdist[0][lane];
  int   gi = sidx[0][lane];
  #pragma unroll
  for (int j = 1; j < 4; ++j) {
    float dj = sdist[j][lane];
    int   ij = sidx[j][lane];
    if (dj < gb) { gb = dj; gi = ij; }
  }

  // ---- epilogue: wave 0 only; all x indices compile-time ----
  if (w == 0) {
    const float* esel = emb + (gi << 6);
    float* zqp = zq + (b << 18) + (h << 6) + lane;
    float lsum = 0.0f;
    #pragma unroll
    for (int d = 0; d < 64; ++d) {
      float v = esel[d];           // per-lane gather (256KB table, L2-resident)
      float df = v - x[d];
      lsum = fmaf(df, df, lsum);
      zqp[d << 12] = v;            // coalesced along w
    }
    #pragma unroll
    for (int off = 32; off > 0; off >>= 1) lsum += __shfl_down(lsum, off, 64);
    if (lane == 0) atomicAdd(ws, lsum);
    atomicAdd(&((int*)ws)[1 + gi], 1);
  }

  // one-hot 1.0: written by the slice-owning wave; its zero store to the same
  // address drained at the barrier above.
  if ((gi >> 8) == w) {
    enc[((size_t)(n0 + lane) << 10) + gi] = 1.0f;
  }
}

__global__ __launch_bounds__(1024) void vq_fin(const float* __restrict__ ws,
                                               float* __restrict__ out) {
  __shared__ float sm[16];
  int t = threadIdx.x;  // 0..1023 = k
  const int* counts = (const int*)ws + 1;
  float c = (float)counts[t];
  float p = c * (1.0f / 131072.0f);
  float s = p * logf(p + 1e-10f);
  #pragma unroll
  for (int off = 32; off > 0; off >>= 1) s += __shfl_down(s, off, 64);
  if ((t & 63) == 0) sm[t >> 6] = s;
  __syncthreads();
  if (t == 0) {
    float v = 0.0f;
    #pragma unroll
    for (int i = 0; i < 16; ++i) v += sm[i];
    out[8388609] = expf(-v);               // perplexity
    float m = ws[0] / 8388608.0f;          // mean (z_q - z)^2
    out[0] = 0.25f * m + m;                // commitment + e2z
  }
}

extern "C" void kernel_launch(void* const* d_in, const int* in_sizes, int n_in,
                              void* d_out, int out_size, void* d_ws, size_t ws_size,
                              hipStream_t stream) {
  const float* ze  = (const float*)d_in[0];
  const float* emb = (const float*)d_in[1];
  float* out = (float*)d_out;
  float* ws  = (float*)d_ws;   // needs 2049 * 4B ≈ 8.2 KB
  vq_prep<<<4, 256, 0, stream>>>(emb, ws);
  vq_main<<<2048, 256, 0, stream>>>(ze, emb, ws, out);
  vq_fin<<<1, 1024, 0, stream>>>(ws, out);
}